// Round 1
// baseline (163.835 us; speedup 1.0000x reference)
//
#include <hip/hip_runtime.h>
#include <hip/hip_bf16.h>
#include <math.h>

#define NF     16      // num features (K of low-rank projection)
#define INF    1024    // in_f
#define NPROTO 4096
#define NROWS  16384
#define OTILE  512     // output cols per block in main_mm
#define NTILE  128     // output rows per block in main_mm

// round f32 -> bf16 (RNE) and return as f32 value
__device__ __forceinline__ float bf16_rne(float x) {
    unsigned u = __float_as_uint(x);
    unsigned r = (u + 0x7FFFu + ((u >> 16) & 1u)) & 0xFFFF0000u;
    return __uint_as_float(r);
}

__device__ __forceinline__ float sigmoid5(float z) {
    return 1.0f / (1.0f + __expf(-5.0f * z));
}

// Butterfly transpose-reduce: v[64] per lane; afterwards lane L holds
// (sum over all 64 lanes of original v[L]) in v[0]. 63 shfl + 63 add.
__device__ __forceinline__ void xreduce64(float* v, int lane) {
#pragma unroll
    for (int s = 32; s >= 1; s >>= 1) {
        bool up = (lane & s) != 0;
#pragma unroll
        for (int j = 0; j < s; ++j) {
            float send = up ? v[j] : v[j + s];
            float recv = __shfl_xor(send, s, 64);
            v[j] = (up ? v[j + s] : v[j]) + recv;
        }
    }
}

// ---------------- Kernel A: build Pe[4096][32] ----------------
// Pe[o][k]    = |theta|*p_a[o][k] - |alpha|*(1 - p_s[o][k])
// Pe[o][16+k] = -|beta|*p_a[o][k]
__global__ __launch_bounds__(256) void build_pe(
    const float* __restrict__ proto, const float* __restrict__ feat,
    const float* __restrict__ theta, const float* __restrict__ alpha,
    const float* __restrict__ beta,  float* __restrict__ Pe)
{
    const int lane  = threadIdx.x & 63;
    const int wid   = threadIdx.x >> 6;
    const int rbase = blockIdx.x * 16 + wid * 4;   // 4 rows per wave
    const int i0    = lane * 16;

    const float th = fabsf(theta[0]);
    const float al = fabsf(alpha[0]);
    const float be = fabsf(beta[0]);

    float q[4][16];
#pragma unroll
    for (int r = 0; r < 4; ++r) {
        const float* wrow = proto + (size_t)(rbase + r) * INF + i0;
        float wb[16];
        float asum = 0.f;
#pragma unroll
        for (int j = 0; j < 16; j += 4) {
            float4 w4 = *(const float4*)(wrow + j);
            wb[j+0] = bf16_rne(w4.x); wb[j+1] = bf16_rne(w4.y);
            wb[j+2] = bf16_rne(w4.z); wb[j+3] = bf16_rne(w4.w);
            asum += fabsf(wb[j+0]) + fabsf(wb[j+1])
                  + fabsf(wb[j+2]) + fabsf(wb[j+3]);
        }
        // group of 64 elems = this lane quad (i0 = lane*16)
        asum += __shfl_xor(asum, 1, 64);
        asum += __shfl_xor(asum, 2, 64);
        float scale = bf16_rne(asum * (1.0f / 64.0f));
        scale = fmaxf(scale, 1e-8f);
        float inv = 1.0f / scale;
#pragma unroll
        for (int j = 0; j < 16; ++j) {
            float t = rintf(bf16_rne(wb[j] * inv));   // jnp.round = half-even
            t = fminf(fmaxf(t, -1.f), 1.f);
            q[r][j] = t * scale;                      // exact in bf16 set
        }
    }

    float acc[64];
#pragma unroll
    for (int i = 0; i < 64; ++i) acc[i] = 0.f;
#pragma unroll
    for (int k = 0; k < NF; ++k) {
        const float* frow = feat + k * INF + i0;
#pragma unroll
        for (int j = 0; j < 16; j += 4) {
            float4 f4 = *(const float4*)(frow + j);
#pragma unroll
            for (int r = 0; r < 4; ++r) {
                acc[r*16+k] = fmaf(q[r][j+0], f4.x, acc[r*16+k]);
                acc[r*16+k] = fmaf(q[r][j+1], f4.y, acc[r*16+k]);
                acc[r*16+k] = fmaf(q[r][j+2], f4.z, acc[r*16+k]);
                acc[r*16+k] = fmaf(q[r][j+3], f4.w, acc[r*16+k]);
            }
        }
    }
    xreduce64(acc, lane);
    // lane holds p_f for (r,k) = (lane>>4, lane&15)
    float pf = acc[0];
    float ps = sigmoid5(pf);
    float pa = pf * ps;
    int row = rbase + (lane >> 4);
    int k   = lane & 15;
    Pe[row * 32 + k]      = th * pa - al * (1.0f - ps);
    Pe[row * 32 + 16 + k] = -be * pa;
}

// ---------------- Kernel B: build Xe[16384][32] ----------------
// Xe[n][k] = x_a[n][k],  Xe[n][16+k] = 1 - x_s[n][k]
__global__ __launch_bounds__(256) void build_xe(
    const float* __restrict__ x, const float* __restrict__ feat,
    float* __restrict__ Xe)
{
    const int lane  = threadIdx.x & 63;
    const int wid   = threadIdx.x >> 6;
    const int rbase = blockIdx.x * 16 + wid * 4;
    const int i0    = lane * 16;

    float4 xv[4][4];
#pragma unroll
    for (int r = 0; r < 4; ++r) {
        const float* xrow = x + (size_t)(rbase + r) * INF + i0;
#pragma unroll
        for (int j = 0; j < 4; ++j) xv[r][j] = *(const float4*)(xrow + j * 4);
    }

    float acc[64];
#pragma unroll
    for (int i = 0; i < 64; ++i) acc[i] = 0.f;
#pragma unroll
    for (int k = 0; k < NF; ++k) {
        const float* frow = feat + k * INF + i0;
#pragma unroll
        for (int j = 0; j < 4; ++j) {
            float4 f4 = *(const float4*)(frow + j * 4);
#pragma unroll
            for (int r = 0; r < 4; ++r) {
                acc[r*16+k] = fmaf(xv[r][j].x, f4.x, acc[r*16+k]);
                acc[r*16+k] = fmaf(xv[r][j].y, f4.y, acc[r*16+k]);
                acc[r*16+k] = fmaf(xv[r][j].z, f4.z, acc[r*16+k]);
                acc[r*16+k] = fmaf(xv[r][j].w, f4.w, acc[r*16+k]);
            }
        }
    }
    xreduce64(acc, lane);
    float xf = acc[0];
    float xs = sigmoid5(xf);
    int row = rbase + (lane >> 4);
    int k   = lane & 15;
    Xe[row * 32 + k]      = xf * xs;
    Xe[row * 32 + 16 + k] = 1.0f - xs;
}

// ---------------- Kernel C: out = Xe (16384x32) @ Pe^T (4096x32) --------
// Thread owns 2 adjacent o columns (Pe rows in 64 VGPRs); Xe rows broadcast
// from LDS (same-address reads, conflict-free); coalesced float2 stores.
__global__ __launch_bounds__(256) void main_mm(
    const float* __restrict__ Xe, const float* __restrict__ Pe,
    float* __restrict__ out)
{
    __shared__ float4 xs4[NTILE * 8];
    const int t     = threadIdx.x;
    const int obase = blockIdx.x * OTILE;
    const int nbase = blockIdx.y * NTILE;

    const float* p0 = Pe + (size_t)(obase + 2 * t) * 32;
    float4 P0[8], P1[8];
#pragma unroll
    for (int j = 0; j < 8; ++j) {
        P0[j] = *(const float4*)(p0 + 4 * j);
        P1[j] = *(const float4*)(p0 + 32 + 4 * j);
    }

    const float4* xsrc = (const float4*)(Xe + (size_t)nbase * 32);
#pragma unroll
    for (int j = 0; j < 4; ++j) xs4[t + 256 * j] = xsrc[t + 256 * j];
    __syncthreads();

    const float* xsf = (const float*)xs4;
    for (int n = 0; n < NTILE; ++n) {
        const float* xr = xsf + n * 32;
        float a0 = 0.f, a1 = 0.f;
#pragma unroll
        for (int j = 0; j < 8; ++j) {
            float4 xq = *(const float4*)(xr + 4 * j);
            a0 = fmaf(xq.x, P0[j].x, a0); a0 = fmaf(xq.y, P0[j].y, a0);
            a0 = fmaf(xq.z, P0[j].z, a0); a0 = fmaf(xq.w, P0[j].w, a0);
            a1 = fmaf(xq.x, P1[j].x, a1); a1 = fmaf(xq.y, P1[j].y, a1);
            a1 = fmaf(xq.z, P1[j].z, a1); a1 = fmaf(xq.w, P1[j].w, a1);
        }
        *(float2*)(out + (size_t)(nbase + n) * NPROTO + obase + 2 * t)
            = make_float2(a0, a1);
    }
}

extern "C" void kernel_launch(void* const* d_in, const int* in_sizes, int n_in,
                              void* d_out, int out_size, void* d_ws, size_t ws_size,
                              hipStream_t stream) {
    const float* x     = (const float*)d_in[0];
    const float* feat  = (const float*)d_in[1];
    const float* proto = (const float*)d_in[2];
    const float* theta = (const float*)d_in[3];
    const float* alpha = (const float*)d_in[4];
    const float* beta  = (const float*)d_in[5];
    float* out = (float*)d_out;

    float* Pe = (float*)d_ws;            // 4096*32*4  = 512 KiB
    float* Xe = Pe + (size_t)NPROTO * 32; // 16384*32*4 = 2 MiB

    build_pe<<<dim3(NPROTO / 16), 256, 0, stream>>>(proto, feat, theta, alpha, beta, Pe);
    build_xe<<<dim3(NROWS / 16), 256, 0, stream>>>(x, feat, Xe);
    main_mm<<<dim3(NPROTO / OTILE, NROWS / NTILE), 256, 0, stream>>>(Xe, Pe, out);
}